// Round 1
// baseline (1298.530 us; speedup 1.0000x reference)
//
#include <hip/hip_runtime.h>
#include <stdint.h>

#define N_TOK 4096
#define C_DIM 1024
#define E_NUM 64
#define TOPK  8
#define P_PAIR (N_TOK*TOPK)     // 32768
#define RMAX  40960             // >= P + E*127 padded rows

typedef __attribute__((ext_vector_type(8))) short bf16x8;
typedef __attribute__((ext_vector_type(4))) float f32x4;

__device__ __forceinline__ uint32_t f2bf(float f){
  uint32_t u = __builtin_bit_cast(uint32_t, f);
  u += 0x7fffu + ((u >> 16) & 1u);   // RNE
  return u >> 16;
}
__device__ __forceinline__ uint32_t pack2bf(float a, float b){
  uint32_t ua = __builtin_bit_cast(uint32_t, a);
  uint32_t ub = __builtin_bit_cast(uint32_t, b);
  ua += 0x7fffu + ((ua >> 16) & 1u);
  ub += 0x7fffu + ((ub >> 16) & 1u);
  return (ua >> 16) | (ub & 0xffff0000u);
}
__device__ __forceinline__ float bf2f(uint32_t u){
  return __builtin_bit_cast(float, u << 16);
}

// ---------------- router: fp64 scores = sigmoid(x @ router_w) ----------------
__global__ __launch_bounds__(256) void router_scores(
    const float* __restrict__ x, const float* __restrict__ rw, double* __restrict__ scores)
{
  __shared__ float xs[16][C_DIM];
  int t0 = blockIdx.x * 16;
  for (int r = 0; r < 16; ++r) {
    int c = threadIdx.x * 4;
    *(float4*)&xs[r][c] = *(const float4*)&x[(size_t)(t0 + r)*C_DIM + c];
  }
  __syncthreads();
  int e = threadIdx.x & 63;
  int slot = threadIdx.x >> 6;
  double acc0=0, acc1=0, acc2=0, acc3=0;
  for (int c = 0; c < C_DIM; ++c) {
    double w = (double)rw[c*E_NUM + e];
    acc0 += (double)xs[slot    ][c] * w;
    acc1 += (double)xs[slot + 4][c] * w;
    acc2 += (double)xs[slot + 8][c] * w;
    acc3 += (double)xs[slot +12][c] * w;
  }
  scores[(size_t)(t0 + slot     )*E_NUM + e] = 1.0/(1.0 + exp(-acc0));
  scores[(size_t)(t0 + slot +  4)*E_NUM + e] = 1.0/(1.0 + exp(-acc1));
  scores[(size_t)(t0 + slot +  8)*E_NUM + e] = 1.0/(1.0 + exp(-acc2));
  scores[(size_t)(t0 + slot + 12)*E_NUM + e] = 1.0/(1.0 + exp(-acc3));
}

// ---------------- top-8 selection (stable, strict >), weights, counts ----------------
__global__ __launch_bounds__(256) void router_topk(
    const double* __restrict__ scores, const float* __restrict__ bias,
    int* __restrict__ topk_idx, float* __restrict__ topk_w, int* __restrict__ counts)
{
  int t = blockIdx.x * blockDim.x + threadIdx.x;
  if (t >= N_TOK) return;
  const double* s = scores + (size_t)t*E_NUM;
  unsigned long long chosen = 0;
  int idx[TOPK]; double val[TOPK]; double wsum = 0;
  for (int k = 0; k < TOPK; ++k) {
    double best = -1e300; int bi = 0;
    for (int e = 0; e < E_NUM; ++e) {
      if ((chosen >> e) & 1ull) continue;
      double v = s[e] + (double)bias[e];
      if (v > best) { best = v; bi = e; }
    }
    chosen |= 1ull << bi;
    idx[k] = bi;
    val[k] = s[bi];                 // weight uses raw score (no bias)
    wsum += s[bi];
    atomicAdd(&counts[bi], 1);
  }
  for (int k = 0; k < TOPK; ++k) {
    topk_idx[t*TOPK + k] = idx[k];
    topk_w[t*TOPK + k] = (float)(val[k] / wsum);
  }
}

// ---------------- per-expert 128-aligned row offsets ----------------
__global__ __launch_bounds__(64) void scan_offsets(const int* __restrict__ counts, int* __restrict__ pad_off)
{
  if (threadIdx.x == 0) {
    int acc = 0;
    for (int e = 0; e < E_NUM; ++e) { pad_off[e] = acc; acc += (counts[e] + 127) & ~127; }
    pad_off[E_NUM] = acc;
  }
}

// ---------------- stable permutation: row -> (token, weight, pair) ----------------
__global__ __launch_bounds__(256) void build_rows(
    const int* __restrict__ topk_idx, const float* __restrict__ topk_w,
    const int* __restrict__ counts, const int* __restrict__ pad_off,
    int* __restrict__ row_token, float* __restrict__ row_wt, int* __restrict__ row_pair)
{
  int e = blockIdx.x;
  int base = pad_off[e];
  __shared__ int wsum_l[4];
  __shared__ int run_s;
  if (threadIdx.x == 0) run_s = 0;
  int lane = threadIdx.x & 63, wv = threadIdx.x >> 6;
  for (int p0 = 0; p0 < P_PAIR; p0 += 256) {
    int p = p0 + threadIdx.x;
    bool flag = (topk_idx[p] == e);
    unsigned long long mb = __ballot(flag);
    int rank = __popcll(mb & ((1ull << lane) - 1ull));
    if (lane == 0) wsum_l[wv] = __popcll(mb);
    __syncthreads();
    int wbase = 0;
    #pragma unroll
    for (int i = 0; i < 4; ++i) if (i < wv) wbase += wsum_l[i];
    int tot = wsum_l[0] + wsum_l[1] + wsum_l[2] + wsum_l[3];
    int run = run_s;
    if (flag) {
      int row = base + run + wbase + rank;
      row_token[row] = p >> 3;
      row_wt[row]    = topk_w[p];
      row_pair[row]  = p;
    }
    __syncthreads();
    if (threadIdx.x == 0) run_s = run + tot;
  }
  __syncthreads();
  int cnt = counts[e];
  int pc = pad_off[e+1] - base;
  for (int r = cnt + threadIdx.x; r < pc; r += 256) {
    row_token[base + r] = -1;
    row_wt[base + r] = 0.f;
    row_pair[base + r] = -1;
  }
}

// ---------------- up-proj GEMM + fused SwiGLU epilogue ----------------
// A = gathered x rows (fp32 -> bf16), B = up weights (fp32 -> bf16), K = C = 1024.
// Output-column tiling interleaves y/g 16-col tiles so silu(g)*y is lane-local.
template<bool SHARED>
__global__ __launch_bounds__(256) void up_gemm(
    const float* __restrict__ X, const float* __restrict__ Wb,
    const int* __restrict__ row_token, const int* __restrict__ pad_off,
    uint16_t* __restrict__ hout, int ldB, int gOff, int ldh)
{
  __shared__ __align__(16) short As[128*32];
  __shared__ __align__(16) short Bs[128*32];
  __shared__ int tok_lds[128];

  const int tid = threadIdx.x;
  const int e = blockIdx.z;
  int row0;
  if constexpr (SHARED) {
    row0 = blockIdx.y * 128;
  } else {
    int pbase = pad_off[e];
    int pcnt  = pad_off[e+1] - pbase;
    if ((int)blockIdx.y * 128 >= pcnt) return;
    row0 = pbase + blockIdx.y * 128;
  }
  const float* W = Wb + (size_t)e * C_DIM * ldB;
  const int c0 = blockIdx.x * 64;

  if (tid < 128) {
    if constexpr (SHARED) tok_lds[tid] = row0 + tid;
    else                  tok_lds[tid] = row_token[row0 + tid];
  }

  const int lane = tid & 63, wid = tid >> 6;
  const int wm = (wid >> 1) * 64, wn = (wid & 1) * 64;
  const int q = lane >> 4, l15 = lane & 15;

  f32x4 acc[4][4];
  #pragma unroll
  for (int i = 0; i < 4; ++i)
    #pragma unroll
    for (int j = 0; j < 4; ++j) { f32x4 z = {0.f,0.f,0.f,0.f}; acc[i][j] = z; }

  const int lnB = tid & 127;
  const int ucB = ((lnB & 16) ? gOff : 0) + c0 + ((lnB >> 5) << 4) + (lnB & 15);
  const int kgB0 = tid >> 7;
  const int sA = tid & 7, rbA = tid >> 3;

  for (int kt = 0; kt < C_DIM/32; ++kt) {
    const int k0 = kt * 32;
    __syncthreads();
    // ---- stage A (gather + cvt), 128x32, XOR-swizzled 16B chunks ----
    #pragma unroll
    for (int p = 0; p < 4; ++p) {
      int r = p*32 + rbA;
      int tok = tok_lds[r];
      float4 v = {0.f,0.f,0.f,0.f};
      if (SHARED || tok >= 0) v = *(const float4*)&X[(size_t)tok*C_DIM + k0 + sA*4];
      uint32_t lo = pack2bf(v.x, v.y), hi = pack2bf(v.z, v.w);
      int off = r*32 + ((((sA>>1) ^ (r&3))) << 3) + (sA&1)*4;
      *(uint2*)&As[off] = make_uint2(lo, hi);
    }
    // ---- stage B (along-k scalar loads + cvt) ----
    #pragma unroll
    for (int p = 0; p < 4; ++p) {
      int kg = kgB0 + 2*p;
      int kk = k0 + kg*4;
      float v0 = W[(size_t)(kk+0)*ldB + ucB];
      float v1 = W[(size_t)(kk+1)*ldB + ucB];
      float v2 = W[(size_t)(kk+2)*ldB + ucB];
      float v3 = W[(size_t)(kk+3)*ldB + ucB];
      uint32_t lo = pack2bf(v0, v1), hi = pack2bf(v2, v3);
      int off = lnB*32 + ((((kg>>1) ^ (lnB&3))) << 3) + (kg&1)*4;
      *(uint2*)&Bs[off] = make_uint2(lo, hi);
    }
    __syncthreads();
    bf16x8 a[4], b[4];
    #pragma unroll
    for (int mi = 0; mi < 4; ++mi) {
      int r = wm + mi*16 + l15;
      a[mi] = *(const bf16x8*)&As[r*32 + ((q ^ (r&3)) << 3)];
    }
    #pragma unroll
    for (int ni = 0; ni < 4; ++ni) {
      int r = wn + ni*16 + l15;
      b[ni] = *(const bf16x8*)&Bs[r*32 + ((q ^ (r&3)) << 3)];
    }
    #pragma unroll
    for (int mi = 0; mi < 4; ++mi)
      #pragma unroll
      for (int ni = 0; ni < 4; ++ni)
        acc[mi][ni] = __builtin_amdgcn_mfma_f32_16x16x32_bf16(a[mi], b[ni], acc[mi][ni], 0, 0, 0);
  }

  // ---- epilogue: h = silu(g) * y, store bf16 ----
  #pragma unroll
  for (int mi = 0; mi < 4; ++mi) {
    int rowb = row0 + wm + mi*16 + q*4;
    #pragma unroll
    for (int jj = 0; jj < 2; ++jj) {
      f32x4 yv = acc[mi][2*jj], gv = acc[mi][2*jj+1];
      int j = (wn >> 5) + jj;
      int hc = c0 + j*16 + l15;
      #pragma unroll
      for (int r = 0; r < 4; ++r) {
        float g = gv[r];
        float sg = 1.f / (1.f + __expf(-g));
        float h = yv[r] * (g * sg);
        hout[(size_t)(rowb + r) * ldh + hc] = (uint16_t)f2bf(h);
      }
    }
  }
}

// ---------------- down-proj GEMM ----------------
// A = bf16 h tiles (direct copy), B = down weights (fp32 -> bf16).
// SHARED: store fp32 to d_out.  EXPERT: scale by gate weight, store bf16 to obuf[pair].
template<bool SHARED>
__global__ __launch_bounds__(256) void down_gemm(
    const uint16_t* __restrict__ H, const float* __restrict__ Wb,
    const float* __restrict__ row_wt, const int* __restrict__ row_pair,
    const int* __restrict__ pad_off, void* __restrict__ outp,
    int ldh, int Kdim)
{
  __shared__ __align__(16) short As[128*32];
  __shared__ __align__(16) short Bs[128*32];
  __shared__ float wt_lds[128];
  __shared__ int pr_lds[128];

  const int tid = threadIdx.x;
  const int e = blockIdx.z;
  int row0;
  if constexpr (SHARED) {
    row0 = blockIdx.y * 128;
  } else {
    int pbase = pad_off[e];
    int pcnt  = pad_off[e+1] - pbase;
    if ((int)blockIdx.y * 128 >= pcnt) return;
    row0 = pbase + blockIdx.y * 128;
  }
  const float* W = Wb + (size_t)e * Kdim * 1024;
  const int c0 = blockIdx.x * 128;

  if (!SHARED && tid < 128) {
    wt_lds[tid] = row_wt[row0 + tid];
    pr_lds[tid] = row_pair[row0 + tid];
  }

  const int lane = tid & 63, wid = tid >> 6;
  const int wm = (wid >> 1) * 64, wn = (wid & 1) * 64;
  const int q = lane >> 4, l15 = lane & 15;

  f32x4 acc[4][4];
  #pragma unroll
  for (int i = 0; i < 4; ++i)
    #pragma unroll
    for (int j = 0; j < 4; ++j) { f32x4 z = {0.f,0.f,0.f,0.f}; acc[i][j] = z; }

  const int lnB = tid & 127;
  const int kgB0 = tid >> 7;
  const int rbA = tid >> 2, cA = tid & 3;

  const int KT = Kdim >> 5;
  for (int kt = 0; kt < KT; ++kt) {
    const int k0 = kt * 32;
    __syncthreads();
    // ---- stage A (bf16 direct, 16B chunks) ----
    #pragma unroll
    for (int p = 0; p < 2; ++p) {
      int r = p*64 + rbA;
      uint4 v = *(const uint4*)&H[(size_t)(row0 + r)*ldh + k0 + cA*8];
      int off = r*32 + ((cA ^ (r&3)) << 3);
      *(uint4*)&As[off] = v;
    }
    // ---- stage B ----
    #pragma unroll
    for (int p = 0; p < 4; ++p) {
      int kg = kgB0 + 2*p;
      int kk = k0 + kg*4;
      float v0 = W[(size_t)(kk+0)*1024 + c0 + lnB];
      float v1 = W[(size_t)(kk+1)*1024 + c0 + lnB];
      float v2 = W[(size_t)(kk+2)*1024 + c0 + lnB];
      float v3 = W[(size_t)(kk+3)*1024 + c0 + lnB];
      uint32_t lo = pack2bf(v0, v1), hi = pack2bf(v2, v3);
      int off = lnB*32 + ((((kg>>1) ^ (lnB&3))) << 3) + (kg&1)*4;
      *(uint2*)&Bs[off] = make_uint2(lo, hi);
    }
    __syncthreads();
    bf16x8 a[4], b[4];
    #pragma unroll
    for (int mi = 0; mi < 4; ++mi) {
      int r = wm + mi*16 + l15;
      a[mi] = *(const bf16x8*)&As[r*32 + ((q ^ (r&3)) << 3)];
    }
    #pragma unroll
    for (int ni = 0; ni < 4; ++ni) {
      int r = wn + ni*16 + l15;
      b[ni] = *(const bf16x8*)&Bs[r*32 + ((q ^ (r&3)) << 3)];
    }
    #pragma unroll
    for (int mi = 0; mi < 4; ++mi)
      #pragma unroll
      for (int ni = 0; ni < 4; ++ni)
        acc[mi][ni] = __builtin_amdgcn_mfma_f32_16x16x32_bf16(a[mi], b[ni], acc[mi][ni], 0, 0, 0);
  }

  if constexpr (SHARED) {
    float* out = (float*)outp;
    #pragma unroll
    for (int mi = 0; mi < 4; ++mi) {
      int rowb = row0 + wm + mi*16 + q*4;
      #pragma unroll
      for (int r = 0; r < 4; ++r)
        #pragma unroll
        for (int ni = 0; ni < 4; ++ni)
          out[(size_t)(rowb + r)*1024 + c0 + wn + ni*16 + l15] = acc[mi][ni][r];
    }
  } else {
    uint16_t* ob = (uint16_t*)outp;
    #pragma unroll
    for (int mi = 0; mi < 4; ++mi) {
      int rloc = wm + mi*16 + q*4;
      #pragma unroll
      for (int r = 0; r < 4; ++r) {
        float wt = wt_lds[rloc + r];
        int pr = pr_lds[rloc + r];
        if (pr >= 0) {
          #pragma unroll
          for (int ni = 0; ni < 4; ++ni)
            ob[(size_t)pr*1024 + c0 + wn + ni*16 + l15] = (uint16_t)f2bf(acc[mi][ni][r] * wt);
        }
      }
    }
  }
}

// ---------------- combine: out[t] += sum_k obuf[pair(t,k)] ----------------
__global__ __launch_bounds__(256) void combine_kernel(
    const uint16_t* __restrict__ obuf, float* __restrict__ out)
{
  int t = blockIdx.x;
  int c = threadIdx.x * 4;
  float a0=0, a1=0, a2=0, a3=0;
  #pragma unroll
  for (int k = 0; k < TOPK; ++k) {
    uint2 v = *(const uint2*)&obuf[((size_t)t*TOPK + k)*1024 + c];
    a0 += bf2f(v.x & 0xffffu); a1 += bf2f(v.x >> 16);
    a2 += bf2f(v.y & 0xffffu); a3 += bf2f(v.y >> 16);
  }
  float4 o = *(float4*)&out[(size_t)t*1024 + c];
  o.x += a0; o.y += a1; o.z += a2; o.w += a3;
  *(float4*)&out[(size_t)t*1024 + c] = o;
}

extern "C" void kernel_launch(void* const* d_in, const int* in_sizes, int n_in,
                              void* d_out, int out_size, void* d_ws, size_t ws_size,
                              hipStream_t stream)
{
  const float* x           = (const float*)d_in[0];
  const float* router_w    = (const float*)d_in[1];
  const float* bias        = (const float*)d_in[2];
  const float* shared_up   = (const float*)d_in[3];
  const float* shared_down = (const float*)d_in[4];
  const float* expert_up   = (const float*)d_in[5];
  const float* expert_down = (const float*)d_in[6];
  float* out = (float*)d_out;

  char* w = (char*)d_ws;
  auto alloc = [&](size_t bytes) -> void* {
    void* p = (void*)w;
    w += (bytes + 255) & ~(size_t)255;
    return p;
  };
  double*  scores    = (double*)  alloc((size_t)N_TOK*E_NUM*8);
  int*     topk_idx  = (int*)     alloc((size_t)N_TOK*TOPK*4);
  float*   topk_w    = (float*)   alloc((size_t)N_TOK*TOPK*4);
  int*     counts    = (int*)     alloc(E_NUM*4);
  int*     pad_off   = (int*)     alloc((E_NUM+1)*4);
  int*     row_token = (int*)     alloc((size_t)RMAX*4);
  float*   row_wt    = (float*)   alloc((size_t)RMAX*4);
  int*     row_pair  = (int*)     alloc((size_t)RMAX*4);
  uint16_t* hbuf     = (uint16_t*)alloc((size_t)RMAX*512*2);
  uint16_t* hsbuf    = (uint16_t*)alloc((size_t)N_TOK*1024*2);
  uint16_t* obuf     = (uint16_t*)alloc((size_t)P_PAIR*1024*2);

  hipMemsetAsync(counts, 0, E_NUM*4, stream);
  router_scores<<<N_TOK/16, 256, 0, stream>>>(x, router_w, scores);
  router_topk<<<N_TOK/256, 256, 0, stream>>>(scores, bias, topk_idx, topk_w, counts);
  scan_offsets<<<1, 64, 0, stream>>>(counts, pad_off);
  build_rows<<<E_NUM, 256, 0, stream>>>(topk_idx, topk_w, counts, pad_off, row_token, row_wt, row_pair);

  // expert up: He=512 -> 8 col-tiles of 64 h-cols; up to 8 row-tiles of 128
  up_gemm<false><<<dim3(8, 8, 64), 256, 0, stream>>>(x, expert_up, row_token, pad_off, hbuf, 1024, 512, 512);
  // shared up: Hs=1024 -> 16 col-tiles; 32 row-tiles
  up_gemm<true><<<dim3(16, 32, 1), 256, 0, stream>>>(x, shared_up, nullptr, nullptr, hsbuf, 2048, 1024, 1024);
  // shared down: writes the full d_out (shared expert contribution)
  down_gemm<true><<<dim3(8, 32, 1), 256, 0, stream>>>(hsbuf, shared_down, nullptr, nullptr, nullptr, (void*)out, 1024, 1024);
  // expert down: scaled per-pair outputs to obuf
  down_gemm<false><<<dim3(8, 8, 64), 256, 0, stream>>>(hbuf, expert_down, row_wt, row_pair, pad_off, (void*)obuf, 512, 512);
  // final combine
  combine_kernel<<<N_TOK, 256, 0, stream>>>(obuf, out);
}

// Round 2
// 1116.736 us; speedup vs baseline: 1.1628x; 1.1628x over previous
//
#include <hip/hip_runtime.h>
#include <stdint.h>

#define N_TOK 4096
#define C_DIM 1024
#define E_NUM 64
#define TOPK  8
#define P_PAIR (N_TOK*TOPK)     // 32768
#define RMAX  40960             // >= P + E*127 padded rows

typedef __attribute__((ext_vector_type(8))) short bf16x8;
typedef __attribute__((ext_vector_type(4))) float f32x4;
typedef uint32_t u32;

__device__ __forceinline__ u32 f2bf(float f){
  u32 u = __builtin_bit_cast(u32, f);
  u += 0x7fffu + ((u >> 16) & 1u);   // RNE
  return u >> 16;
}
__device__ __forceinline__ u32 pack2bf(float a, float b){
  u32 ua = __builtin_bit_cast(u32, a);
  u32 ub = __builtin_bit_cast(u32, b);
  ua += 0x7fffu + ((ua >> 16) & 1u);
  ub += 0x7fffu + ((ub >> 16) & 1u);
  return (ua >> 16) | (ub & 0xffff0000u);
}
__device__ __forceinline__ float bf2f(u32 u){
  return __builtin_bit_cast(float, u << 16);
}

// async global->LDS, 16B per lane. LDS dest = wave-uniform base + lane*16.
__device__ __forceinline__ void async_copy16(const void* g, void* l) {
  __builtin_amdgcn_global_load_lds((const __attribute__((address_space(1))) u32*)g,
                                   (__attribute__((address_space(3))) u32*)l, 16, 0, 0);
}

// ---------------- router: fp64 scores = sigmoid(x @ router_w) ----------------
__global__ __launch_bounds__(256) void router_scores(
    const float* __restrict__ x, const float* __restrict__ rw, double* __restrict__ scores)
{
  __shared__ float xs[16][C_DIM];
  int t0 = blockIdx.x * 16;
  for (int r = 0; r < 16; ++r) {
    int c = threadIdx.x * 4;
    *(float4*)&xs[r][c] = *(const float4*)&x[(size_t)(t0 + r)*C_DIM + c];
  }
  __syncthreads();
  int e = threadIdx.x & 63;
  int slot = threadIdx.x >> 6;
  double acc0=0, acc1=0, acc2=0, acc3=0;
  for (int c = 0; c < C_DIM; ++c) {
    double w = (double)rw[c*E_NUM + e];
    acc0 += (double)xs[slot    ][c] * w;
    acc1 += (double)xs[slot + 4][c] * w;
    acc2 += (double)xs[slot + 8][c] * w;
    acc3 += (double)xs[slot +12][c] * w;
  }
  scores[(size_t)(t0 + slot     )*E_NUM + e] = 1.0/(1.0 + exp(-acc0));
  scores[(size_t)(t0 + slot +  4)*E_NUM + e] = 1.0/(1.0 + exp(-acc1));
  scores[(size_t)(t0 + slot +  8)*E_NUM + e] = 1.0/(1.0 + exp(-acc2));
  scores[(size_t)(t0 + slot + 12)*E_NUM + e] = 1.0/(1.0 + exp(-acc3));
}

// ---------------- top-8 selection (stable, strict >), weights, counts ----------------
__global__ __launch_bounds__(256) void router_topk(
    const double* __restrict__ scores, const float* __restrict__ bias,
    int* __restrict__ topk_idx, float* __restrict__ topk_w, int* __restrict__ counts)
{
  int t = blockIdx.x * blockDim.x + threadIdx.x;
  if (t >= N_TOK) return;
  const double* s = scores + (size_t)t*E_NUM;
  unsigned long long chosen = 0;
  int idx[TOPK]; double val[TOPK]; double wsum = 0;
  for (int k = 0; k < TOPK; ++k) {
    double best = -1e300; int bi = 0;
    for (int e = 0; e < E_NUM; ++e) {
      if ((chosen >> e) & 1ull) continue;
      double v = s[e] + (double)bias[e];
      if (v > best) { best = v; bi = e; }
    }
    chosen |= 1ull << bi;
    idx[k] = bi;
    val[k] = s[bi];
    wsum += s[bi];
    atomicAdd(&counts[bi], 1);
  }
  for (int k = 0; k < TOPK; ++k) {
    topk_idx[t*TOPK + k] = idx[k];
    topk_w[t*TOPK + k] = (float)(val[k] / wsum);
  }
}

// ---------------- per-expert 128-aligned row offsets ----------------
__global__ __launch_bounds__(64) void scan_offsets(const int* __restrict__ counts, int* __restrict__ pad_off)
{
  if (threadIdx.x == 0) {
    int acc = 0;
    for (int e = 0; e < E_NUM; ++e) { pad_off[e] = acc; acc += (counts[e] + 127) & ~127; }
    pad_off[E_NUM] = acc;
  }
}

// ---------------- stable permutation: row -> (token, weight, pair) ----------------
__global__ __launch_bounds__(256) void build_rows(
    const int* __restrict__ topk_idx, const float* __restrict__ topk_w,
    const int* __restrict__ counts, const int* __restrict__ pad_off,
    int* __restrict__ row_token, float* __restrict__ row_wt, int* __restrict__ row_pair)
{
  int e = blockIdx.x;
  int base = pad_off[e];
  __shared__ int wsum_l[4];
  __shared__ int run_s;
  if (threadIdx.x == 0) run_s = 0;
  int lane = threadIdx.x & 63, wv = threadIdx.x >> 6;
  for (int p0 = 0; p0 < P_PAIR; p0 += 256) {
    int p = p0 + threadIdx.x;
    bool flag = (topk_idx[p] == e);
    unsigned long long mb = __ballot(flag);
    int rank = __popcll(mb & ((1ull << lane) - 1ull));
    if (lane == 0) wsum_l[wv] = __popcll(mb);
    __syncthreads();
    int wbase = 0;
    #pragma unroll
    for (int i = 0; i < 4; ++i) if (i < wv) wbase += wsum_l[i];
    int tot = wsum_l[0] + wsum_l[1] + wsum_l[2] + wsum_l[3];
    int run = run_s;
    if (flag) {
      int row = base + run + wbase + rank;
      row_token[row] = p >> 3;
      row_wt[row]    = topk_w[p];
      row_pair[row]  = p;
    }
    __syncthreads();
    if (threadIdx.x == 0) run_s = run + tot;
  }
  __syncthreads();
  int cnt = counts[e];
  int pc = pad_off[e+1] - base;
  for (int r = cnt + threadIdx.x; r < pc; r += 256) {
    row_token[base + r] = -1;
    row_wt[base + r] = 0.f;
    row_pair[base + r] = -1;
  }
}

// ---------------- convert x: fp32 -> bf16 row-major ----------------
__global__ __launch_bounds__(256) void cvt_x(const float* __restrict__ in, uint16_t* __restrict__ out)
{
  int i = blockIdx.x * 256 + threadIdx.x;
  float4 a = *(const float4*)&in[(size_t)i*8];
  float4 b = *(const float4*)&in[(size_t)i*8 + 4];
  uint4 o;
  o.x = pack2bf(a.x, a.y); o.y = pack2bf(a.z, a.w);
  o.z = pack2bf(b.x, b.y); o.w = pack2bf(b.z, b.w);
  *(uint4*)&out[(size_t)i*8] = o;
}

// ---------------- transpose+convert: fp32 [B][R][Cc] -> bf16 [B][Cc][R] ----------------
__global__ __launch_bounds__(256) void transpose_cvt(
    const float* __restrict__ in, uint16_t* __restrict__ out, int R, int Cc)
{
  __shared__ uint16_t tile[64][72];
  const size_t bo = (size_t)blockIdx.z * R * Cc;
  int c0 = blockIdx.x * 64;
  int r0 = blockIdx.y * 64;
  int tx = threadIdx.x & 15, ty = threadIdx.x >> 4;
  #pragma unroll
  for (int i = 0; i < 4; ++i) {
    int r = ty + i*16;
    float4 v = *(const float4*)&in[bo + (size_t)(r0 + r)*Cc + c0 + tx*4];
    *(uint2*)&tile[r][tx*4] = make_uint2(pack2bf(v.x, v.y), pack2bf(v.z, v.w));
  }
  __syncthreads();
  #pragma unroll
  for (int i = 0; i < 2; ++i) {
    int u = threadIdx.x + 256*i;
    int c = u >> 3, rc = u & 7;
    uint16_t tmp[8];
    #pragma unroll
    for (int j = 0; j < 8; ++j) tmp[j] = tile[rc*8 + j][c];
    *(uint4*)&out[bo + (size_t)(c0 + c)*R + r0 + rc*8] = *(uint4*)tmp;
  }
}

// ---------------- up-proj GEMM + fused SwiGLU (bf16, async staging, frag-order LDS) ----------------
// Xb: bf16 row-major [*,1024].  Wt: bf16 col-major [e][2*He][1024].
// LDS layout: 8 groups of 16 rows/cols, each group 512 shorts in MFMA frag order (lane-linear).
template<bool SHARED>
__global__ __launch_bounds__(256) void up_gemm2(
    const uint16_t* __restrict__ Xb, const uint16_t* __restrict__ Wt,
    const int* __restrict__ row_token, const int* __restrict__ pad_off,
    uint16_t* __restrict__ hout, int He, int ldh)
{
  __shared__ __align__(16) uint16_t As[8*512];
  __shared__ __align__(16) uint16_t Bs[8*512];
  __shared__ int tok_lds[128];

  const int tid = threadIdx.x;
  int e, xt, yt;
  if constexpr (SHARED) {
    e = 0; xt = blockIdx.x; yt = blockIdx.y;
  } else {
    int f = blockIdx.x;            // XCD-pinned decode: expert -> single XCD (id%8 round-robin)
    int s = f >> 3;
    e = (f & 7) * 8 + (s >> 6);
    int unit = s & 63;
    xt = unit & 7; yt = unit >> 3;
  }
  int row0;
  if constexpr (SHARED) {
    row0 = yt * 128;
  } else {
    int pbase = pad_off[e], pcnt = pad_off[e+1] - pbase;
    if (yt * 128 >= pcnt) return;
    row0 = pbase + yt * 128;
  }
  const int c0 = xt * 64;   // h-col base
  const uint16_t* W = Wt + (size_t)e * (2*He) * 1024;

  if (tid < 128)
    tok_lds[tid] = SHARED ? (row0 + tid) : row_token[row0 + tid];
  __syncthreads();

  const int lane = tid & 63, wid = tid >> 6;
  const int l15 = lane & 15, q = lane >> 4;
  const int wm = (wid >> 1) * 64, wn = (wid & 1) * 64;

  const int gp0 = 2*wid, gp1 = 2*wid + 1;
  int tA0 = tok_lds[gp0*16 + l15]; if (tA0 < 0) tA0 = 0;
  int tA1 = tok_lds[gp1*16 + l15]; if (tA1 < 0) tA1 = 0;
  const uint16_t* gA0 = Xb + (size_t)tA0*C_DIM + q*8;
  const uint16_t* gA1 = Xb + (size_t)tA1*C_DIM + q*8;
  const int nc0 = ((gp0 & 1) ? He : 0) + c0 + (gp0 >> 1)*16 + l15;
  const int nc1 = ((gp1 & 1) ? He : 0) + c0 + (gp1 >> 1)*16 + l15;
  const uint16_t* gB0 = W + (size_t)nc0*C_DIM + q*8;
  const uint16_t* gB1 = W + (size_t)nc1*C_DIM + q*8;
  uint16_t* lA0 = &As[gp0*512]; uint16_t* lA1 = &As[gp1*512];
  uint16_t* lB0 = &Bs[gp0*512]; uint16_t* lB1 = &Bs[gp1*512];

  f32x4 acc[4][4];
  #pragma unroll
  for (int i = 0; i < 4; ++i)
    #pragma unroll
    for (int j = 0; j < 4; ++j) { f32x4 z = {0.f,0.f,0.f,0.f}; acc[i][j] = z; }

  for (int k0 = 0; k0 < C_DIM; k0 += 32) {
    __syncthreads();                   // prev-iter frag reads done before overwrite
    async_copy16(gA0 + k0, lA0);
    async_copy16(gA1 + k0, lA1);
    async_copy16(gB0 + k0, lB0);
    async_copy16(gB1 + k0, lB1);
    __syncthreads();                   // vmcnt(0) drain + barrier -> tiles visible
    bf16x8 a[4], b[4];
    #pragma unroll
    for (int mi = 0; mi < 4; ++mi)
      a[mi] = *(const bf16x8*)&As[(wm/16 + mi)*512 + lane*8];
    #pragma unroll
    for (int ni = 0; ni < 4; ++ni)
      b[ni] = *(const bf16x8*)&Bs[(wn/16 + ni)*512 + lane*8];
    #pragma unroll
    for (int mi = 0; mi < 4; ++mi)
      #pragma unroll
      for (int ni = 0; ni < 4; ++ni)
        acc[mi][ni] = __builtin_amdgcn_mfma_f32_16x16x32_bf16(a[mi], b[ni], acc[mi][ni], 0, 0, 0);
  }

  // epilogue: h = silu(g) * y  (even group = y, odd group = g)
  #pragma unroll
  for (int mi = 0; mi < 4; ++mi) {
    int rowb = row0 + wm + mi*16 + q*4;
    #pragma unroll
    for (int jj = 0; jj < 2; ++jj) {
      f32x4 yv = acc[mi][2*jj], gv = acc[mi][2*jj+1];
      int j = (wn >> 5) + jj;
      int hc = c0 + j*16 + l15;
      #pragma unroll
      for (int r = 0; r < 4; ++r) {
        float g = gv[r];
        float sg = 1.f / (1.f + __expf(-g));
        float h = yv[r] * (g * sg);
        hout[(size_t)(rowb + r) * ldh + hc] = (uint16_t)f2bf(h);
      }
    }
  }
}

// ---------------- down-proj GEMM (bf16, async staging, frag-order LDS) ----------------
// H: bf16 row-major [*, ldh].  Wt: bf16 col-major [e][1024][Kdim].
template<bool SHARED>
__global__ __launch_bounds__(256) void down_gemm2(
    const uint16_t* __restrict__ H, const uint16_t* __restrict__ Wt,
    const float* __restrict__ row_wt, const int* __restrict__ row_pair,
    const int* __restrict__ pad_off, void* __restrict__ outp,
    int ldh, int Kdim)
{
  __shared__ __align__(16) uint16_t As[8*512];
  __shared__ __align__(16) uint16_t Bs[8*512];
  __shared__ float wt_lds[128];
  __shared__ int pr_lds[128];

  const int tid = threadIdx.x;
  int e, xt, yt;
  if constexpr (SHARED) {
    e = 0; xt = blockIdx.x; yt = blockIdx.y;
  } else {
    int f = blockIdx.x;
    int s = f >> 3;
    e = (f & 7) * 8 + (s >> 6);
    int unit = s & 63;
    xt = unit & 7; yt = unit >> 3;
  }
  int row0;
  if constexpr (SHARED) {
    row0 = yt * 128;
  } else {
    int pbase = pad_off[e], pcnt = pad_off[e+1] - pbase;
    if (yt * 128 >= pcnt) return;
    row0 = pbase + yt * 128;
  }
  const int c0 = xt * 128;
  const uint16_t* W = Wt + (size_t)e * 1024 * Kdim;

  if (!SHARED && tid < 128) {
    wt_lds[tid] = row_wt[row0 + tid];
    pr_lds[tid] = row_pair[row0 + tid];
  }
  __syncthreads();

  const int lane = tid & 63, wid = tid >> 6;
  const int l15 = lane & 15, q = lane >> 4;
  const int wm = (wid >> 1) * 64, wn = (wid & 1) * 64;

  const int gp0 = 2*wid, gp1 = 2*wid + 1;
  const uint16_t* gA0 = H + (size_t)(row0 + gp0*16 + l15)*ldh + q*8;
  const uint16_t* gA1 = H + (size_t)(row0 + gp1*16 + l15)*ldh + q*8;
  const uint16_t* gB0 = W + (size_t)(c0 + gp0*16 + l15)*Kdim + q*8;
  const uint16_t* gB1 = W + (size_t)(c0 + gp1*16 + l15)*Kdim + q*8;
  uint16_t* lA0 = &As[gp0*512]; uint16_t* lA1 = &As[gp1*512];
  uint16_t* lB0 = &Bs[gp0*512]; uint16_t* lB1 = &Bs[gp1*512];

  f32x4 acc[4][4];
  #pragma unroll
  for (int i = 0; i < 4; ++i)
    #pragma unroll
    for (int j = 0; j < 4; ++j) { f32x4 z = {0.f,0.f,0.f,0.f}; acc[i][j] = z; }

  for (int k0 = 0; k0 < Kdim; k0 += 32) {
    __syncthreads();
    async_copy16(gA0 + k0, lA0);
    async_copy16(gA1 + k0, lA1);
    async_copy16(gB0 + k0, lB0);
    async_copy16(gB1 + k0, lB1);
    __syncthreads();
    bf16x8 a[4], b[4];
    #pragma unroll
    for (int mi = 0; mi < 4; ++mi)
      a[mi] = *(const bf16x8*)&As[(wm/16 + mi)*512 + lane*8];
    #pragma unroll
    for (int ni = 0; ni < 4; ++ni)
      b[ni] = *(const bf16x8*)&Bs[(wn/16 + ni)*512 + lane*8];
    #pragma unroll
    for (int mi = 0; mi < 4; ++mi)
      #pragma unroll
      for (int ni = 0; ni < 4; ++ni)
        acc[mi][ni] = __builtin_amdgcn_mfma_f32_16x16x32_bf16(a[mi], b[ni], acc[mi][ni], 0, 0, 0);
  }

  if constexpr (SHARED) {
    float* out = (float*)outp;
    #pragma unroll
    for (int mi = 0; mi < 4; ++mi) {
      int rowb = row0 + wm + mi*16 + q*4;
      #pragma unroll
      for (int r = 0; r < 4; ++r)
        #pragma unroll
        for (int ni = 0; ni < 4; ++ni)
          out[(size_t)(rowb + r)*1024 + c0 + wn + ni*16 + l15] = acc[mi][ni][r];
    }
  } else {
    uint16_t* ob = (uint16_t*)outp;
    #pragma unroll
    for (int mi = 0; mi < 4; ++mi) {
      int rloc = wm + mi*16 + q*4;
      #pragma unroll
      for (int r = 0; r < 4; ++r) {
        float wt = wt_lds[rloc + r];
        int pr = pr_lds[rloc + r];
        if (pr >= 0) {
          #pragma unroll
          for (int ni = 0; ni < 4; ++ni)
            ob[(size_t)pr*1024 + c0 + wn + ni*16 + l15] = (uint16_t)f2bf(acc[mi][ni][r] * wt);
        }
      }
    }
  }
}

// ---------------- combine: out[t] += sum_k obuf[pair(t,k)] ----------------
__global__ __launch_bounds__(256) void combine_kernel(
    const uint16_t* __restrict__ obuf, float* __restrict__ out)
{
  int t = blockIdx.x;
  int c = threadIdx.x * 4;
  float a0=0, a1=0, a2=0, a3=0;
  #pragma unroll
  for (int k = 0; k < TOPK; ++k) {
    uint2 v = *(const uint2*)&obuf[((size_t)t*TOPK + k)*1024 + c];
    a0 += bf2f(v.x & 0xffffu); a1 += bf2f(v.x >> 16);
    a2 += bf2f(v.y & 0xffffu); a3 += bf2f(v.y >> 16);
  }
  float4 o = *(float4*)&out[(size_t)t*1024 + c];
  o.x += a0; o.y += a1; o.z += a2; o.w += a3;
  *(float4*)&out[(size_t)t*1024 + c] = o;
}

extern "C" void kernel_launch(void* const* d_in, const int* in_sizes, int n_in,
                              void* d_out, int out_size, void* d_ws, size_t ws_size,
                              hipStream_t stream)
{
  const float* x           = (const float*)d_in[0];
  const float* router_w    = (const float*)d_in[1];
  const float* bias        = (const float*)d_in[2];
  const float* shared_up   = (const float*)d_in[3];
  const float* shared_down = (const float*)d_in[4];
  const float* expert_up   = (const float*)d_in[5];
  const float* expert_down = (const float*)d_in[6];
  float* out = (float*)d_out;

  char* w = (char*)d_ws;
  auto alloc = [&](size_t bytes) -> void* {
    void* p = (void*)w;
    w += (bytes + 255) & ~(size_t)255;
    return p;
  };
  double*  scores    = (double*)  alloc((size_t)N_TOK*E_NUM*8);
  int*     topk_idx  = (int*)     alloc((size_t)N_TOK*TOPK*4);
  float*   topk_w    = (float*)   alloc((size_t)N_TOK*TOPK*4);
  int*     counts    = (int*)     alloc(E_NUM*4);
  int*     pad_off   = (int*)     alloc((E_NUM+1)*4);
  int*     row_token = (int*)     alloc((size_t)RMAX*4);
  float*   row_wt    = (float*)   alloc((size_t)RMAX*4);
  int*     row_pair  = (int*)     alloc((size_t)RMAX*4);
  uint16_t* xbf      = (uint16_t*)alloc((size_t)N_TOK*C_DIM*2);            // 8 MB
  uint16_t* eup_t    = (uint16_t*)alloc((size_t)E_NUM*1024*1024*2);        // 128 MB  [e][n=1024][k=1024]
  uint16_t* edn_t    = (uint16_t*)alloc((size_t)E_NUM*1024*512*2);         // 64 MB   [e][n=1024][k=512]
  uint16_t* sup_t    = (uint16_t*)alloc((size_t)2048*1024*2);              // 4 MB    [n=2048][k=1024]
  uint16_t* sdn_t    = (uint16_t*)alloc((size_t)1024*1024*2);              // 2 MB    [n=1024][k=1024]
  uint16_t* hbuf     = (uint16_t*)alloc((size_t)RMAX*512*2);               // 40 MB
  uint16_t* hsbuf    = (uint16_t*)alloc((size_t)N_TOK*1024*2);             // 8 MB
  uint16_t* obuf     = (uint16_t*)alloc((size_t)P_PAIR*1024*2);            // 64 MB

  hipMemsetAsync(counts, 0, E_NUM*4, stream);

  // weight/x conversion passes
  cvt_x<<<(N_TOK*C_DIM)/(256*8), 256, 0, stream>>>(x, xbf);
  transpose_cvt<<<dim3(16, 16, 64), 256, 0, stream>>>(expert_up,   eup_t, 1024, 1024);
  transpose_cvt<<<dim3(16,  8, 64), 256, 0, stream>>>(expert_down, edn_t,  512, 1024);
  transpose_cvt<<<dim3(32, 16,  1), 256, 0, stream>>>(shared_up,   sup_t, 1024, 2048);
  transpose_cvt<<<dim3(16, 16,  1), 256, 0, stream>>>(shared_down, sdn_t, 1024, 1024);

  // routing
  router_scores<<<N_TOK/16, 256, 0, stream>>>(x, router_w, scores);
  router_topk<<<N_TOK/256, 256, 0, stream>>>(scores, bias, topk_idx, topk_w, counts);
  scan_offsets<<<1, 64, 0, stream>>>(counts, pad_off);
  build_rows<<<E_NUM, 256, 0, stream>>>(topk_idx, topk_w, counts, pad_off, row_token, row_wt, row_pair);

  // GEMMs
  up_gemm2<false><<<4096, 256, 0, stream>>>(xbf, eup_t, row_token, pad_off, hbuf, 512, 512);
  up_gemm2<true><<<dim3(16, 32), 256, 0, stream>>>(xbf, sup_t, nullptr, nullptr, hsbuf, 1024, 1024);
  down_gemm2<true><<<dim3(8, 32), 256, 0, stream>>>(hsbuf, sdn_t, nullptr, nullptr, nullptr, (void*)out, 1024, 1024);
  down_gemm2<false><<<4096, 256, 0, stream>>>(hbuf, edn_t, row_wt, row_pair, pad_off, (void*)obuf, 512, 512);
  combine_kernel<<<N_TOK, 256, 0, stream>>>(obuf, out);
}